// Round 2
// baseline (432.764 us; speedup 1.0000x reference)
//
#include <hip/hip_runtime.h>
#include <hip/hip_bf16.h>

// StaticW8A8Int8Linear: M=8192, K=4096, N=4096
//   x_q   = clip(rint(x / input_scale), -128, 127) int8        [M,K]
//   acc   = x_q @ weight(int8)                      int32      [M,N]
//   out   = float(acc) * (input_scale*weight_scale) + bias     fp32
//
// ws layout: Aq int8 [M][K] (33,554,432 B) | Bt int8 [N][K] (16,777,216 B)
// total 48 MiB required in d_ws.

#define M_DIM 8192
#define K_DIM 4096
#define N_DIM 4096

typedef int i32x4 __attribute__((ext_vector_type(4)));

__device__ __forceinline__ void async_ld16(const void* g, void* l) {
  __builtin_amdgcn_global_load_lds(
      (const __attribute__((address_space(1))) void*)g,
      (__attribute__((address_space(3))) void*)l, 16, 0, 0);
}

// ---------------------------------------------------------------- quantize x
// 16 fp32 -> 16 int8 per thread. Exact division + rintf matches
// jnp.round(x / s) (round-half-even) bitwise; clamp matches jnp.clip.
__global__ __launch_bounds__(256) void quant_x(const float* __restrict__ x,
                                               const float* __restrict__ sptr,
                                               char* __restrict__ xq) {
  const float s = sptr[0];
  const size_t base = ((size_t)blockIdx.x * 256 + threadIdx.x) * 16;
  const float4* xv = (const float4*)(x + base);
  union { char c[16]; i32x4 v; } u;
#pragma unroll
  for (int q = 0; q < 4; ++q) {
    float4 f = xv[q];
    float a = fminf(127.f, fmaxf(-128.f, rintf(f.x / s)));
    float b = fminf(127.f, fmaxf(-128.f, rintf(f.y / s)));
    float c = fminf(127.f, fmaxf(-128.f, rintf(f.z / s)));
    float d = fminf(127.f, fmaxf(-128.f, rintf(f.w / s)));
    u.c[q * 4 + 0] = (char)(int)a;
    u.c[q * 4 + 1] = (char)(int)b;
    u.c[q * 4 + 2] = (char)(int)c;
    u.c[q * 4 + 3] = (char)(int)d;
  }
  *(i32x4*)(xq + base) = u.v;
}

// ------------------------------------------- weight int32[K][N] -> int8 Bt[N][K]
// 64x64 tile per block through LDS. Reads coalesced along N, writes
// coalesced 16B along K.
__global__ __launch_bounds__(256) void wconv(const int* __restrict__ w,
                                             char* __restrict__ bt) {
  __shared__ alignas(16) char tile[64][80];  // stride 80: 16B-aligned rows, bank-spread
  const int k0 = blockIdx.x * 64;
  const int n0 = blockIdx.y * 64;
  const int t = threadIdx.x;
  const int kr = t >> 4;         // 0..15
  const int nc = (t & 15) * 4;   // 0..60
#pragma unroll
  for (int it = 0; it < 4; ++it) {
    int k = it * 16 + kr;
    int4 v = *(const int4*)(w + (size_t)(k0 + k) * N_DIM + n0 + nc);
    tile[nc + 0][k] = (char)v.x;
    tile[nc + 1][k] = (char)v.y;
    tile[nc + 2][k] = (char)v.z;
    tile[nc + 3][k] = (char)v.w;
  }
  __syncthreads();
  const int n = t >> 2;          // 0..63
  const int ks = (t & 3) * 16;   // 0..48
  int4 o = *(const int4*)&tile[n][ks];
  *(int4*)(bt + (size_t)(n0 + n) * K_DIM + k0 + ks) = o;
}

// ----------------------------------------------------------------- i8 GEMM
// m97-structure: 128x128 tile, BK=128 bytes (int8), 4 waves (2x2) x 64x64 out,
// mfma_i32_16x16x64_i8, global_load_lds(16B) staging, XOR swizzle
// (col ^= (row&7)<<4) applied to the global SOURCE (LDS dest linear) and to
// the ds_read address. 2 barriers per K-step.
__global__ __launch_bounds__(256) void gemm_i8(
    const char* __restrict__ Aq, const char* __restrict__ Bt,
    const float* __restrict__ bias,
    const float* __restrict__ is_ptr, const float* __restrict__ ws_ptr,
    float* __restrict__ out) {
  __shared__ alignas(16) char ldsA[128 * 128];
  __shared__ alignas(16) char ldsB[128 * 128];

  // XCD-aware bijective swizzle (grid = 2048, divisible by 8)
  const int nbn = N_DIM / 128;  // 32
  const int bid = blockIdx.x;
  const int cpx = gridDim.x >> 3;
  const int swz = (bid & 7) * cpx + (bid >> 3);
  const int bm0 = (swz / nbn) * 128;
  const int bn0 = (swz % nbn) * 128;

  const int t = threadIdx.x;
  const int lane = t & 63;
  const int wave = t >> 6;   // 0..3
  const int wm = wave >> 1;  // 0..1
  const int wn = wave & 1;   // 0..1
  const int lr = lane & 15;
  const int lkb = (lane >> 4) << 4;  // 0,16,32,48: k-byte offset within K=64 group

  // staging: thread t covers LDS row sr=t>>3, 16B slot (t&7); source col is
  // inverse-swizzled so that swizzled ds_reads see the natural layout.
  const int sr = t >> 3;                     // 0..31
  const int sc = ((t & 7) ^ (sr & 7)) << 4;  // pre-swizzled source byte col
  const char* aSrc = Aq + (size_t)(bm0 + sr) * K_DIM + sc;
  const char* bSrc = Bt + (size_t)(bn0 + sr) * K_DIM + sc;
  char* aDst = &ldsA[t * 16];
  char* bDst = &ldsB[t * 16];

  // ds_read offsets (constant over K loop)
  int aOff[4][2], bOff[4][2];
#pragma unroll
  for (int m = 0; m < 4; ++m) {
    int row = wm * 64 + m * 16 + lr;
#pragma unroll
    for (int ks = 0; ks < 2; ++ks) {
      int col = ks * 64 + lkb;
      aOff[m][ks] = row * 128 + (col ^ ((row & 7) << 4));
    }
  }
#pragma unroll
  for (int n = 0; n < 4; ++n) {
    int row = wn * 64 + n * 16 + lr;
#pragma unroll
    for (int ks = 0; ks < 2; ++ks) {
      int col = ks * 64 + lkb;
      bOff[n][ks] = row * 128 + (col ^ ((row & 7) << 4));
    }
  }

  i32x4 acc[4][4];
#pragma unroll
  for (int m = 0; m < 4; ++m)
#pragma unroll
    for (int n = 0; n < 4; ++n) acc[m][n] = (i32x4)(0);

  const int NT = K_DIM / 128;  // 32
  for (int kt = 0; kt < NT; ++kt) {
    const size_t ko = (size_t)kt * 128;
#pragma unroll
    for (int it = 0; it < 4; ++it) {
      async_ld16(aSrc + ko + (size_t)it * 32 * K_DIM, aDst + it * 4096);
      async_ld16(bSrc + ko + (size_t)it * 32 * K_DIM, bDst + it * 4096);
    }
    __syncthreads();  // vmcnt(0) drained by compiler -> tile ready
#pragma unroll
    for (int ks = 0; ks < 2; ++ks) {
      i32x4 aF[4], bF[4];
#pragma unroll
      for (int m = 0; m < 4; ++m) aF[m] = *(const i32x4*)&ldsA[aOff[m][ks]];
#pragma unroll
      for (int n = 0; n < 4; ++n) bF[n] = *(const i32x4*)&ldsB[bOff[n][ks]];
#pragma unroll
      for (int m = 0; m < 4; ++m)
#pragma unroll
        for (int n = 0; n < 4; ++n)
          acc[m][n] = __builtin_amdgcn_mfma_i32_16x16x64_i8(aF[m], bF[n],
                                                            acc[m][n], 0, 0, 0);
    }
    __syncthreads();  // all reads done before next-tile staging overwrites
  }

  // epilogue: C/D layout col=lane&15, row=(lane>>4)*4+reg
  const float s = is_ptr[0] * ws_ptr[0];
  const int colBase = bn0 + wn * 64 + lr;
  float bv[4];
#pragma unroll
  for (int n = 0; n < 4; ++n) bv[n] = bias[colBase + n * 16];
  const int rowBase = bm0 + wm * 64 + ((lane >> 4) << 2);
#pragma unroll
  for (int m = 0; m < 4; ++m) {
#pragma unroll
    for (int j = 0; j < 4; ++j) {
      const int row = rowBase + m * 16 + j;
      float* orow = out + (size_t)row * N_DIM;
#pragma unroll
      for (int n = 0; n < 4; ++n)
        orow[colBase + n * 16] = (float)acc[m][n][j] * s + bv[n];
    }
  }
}

extern "C" void kernel_launch(void* const* d_in, const int* in_sizes, int n_in,
                              void* d_out, int out_size, void* d_ws, size_t ws_size,
                              hipStream_t stream) {
  const float* x    = (const float*)d_in[0];
  const int*   w    = (const int*)d_in[1];
  const float* bias = (const float*)d_in[2];
  const float* isc  = (const float*)d_in[3];
  const float* wsc  = (const float*)d_in[4];
  float* out = (float*)d_out;

  char* Aq = (char*)d_ws;                                   // 32 MiB
  char* Bt = (char*)d_ws + (size_t)M_DIM * K_DIM;           // 16 MiB
  // requires ws_size >= 48 MiB

  quant_x<<<(M_DIM * K_DIM) / (256 * 16), 256, 0, stream>>>(x, isc, Aq);

  dim3 tg(K_DIM / 64, N_DIM / 64);
  wconv<<<tg, 256, 0, stream>>>(w, Bt);

  gemm_i8<<<(M_DIM / 128) * (N_DIM / 128), 256, 0, stream>>>(Aq, Bt, bias, isc,
                                                             wsc, out);
}

// Round 3
// 396.065 us; speedup vs baseline: 1.0927x; 1.0927x over previous
//
#include <hip/hip_runtime.h>
#include <hip/hip_bf16.h>

// StaticW8A8Int8Linear: M=8192, K=4096, N=4096
//   x_q = clip(rint(x/is),-128,127) i8;  acc = x_q @ w(i8) i32
//   out = float(acc)*(is*ws) + bias  (fp32)
// ws: Aq i8 [M][K] (32 MiB) | Bt i8 [N][K] (16 MiB)

#define M_DIM 8192
#define K_DIM 4096
#define N_DIM 4096

typedef int i32x4 __attribute__((ext_vector_type(4)));

__device__ __forceinline__ void async_ld16(const void* g, void* l) {
  __builtin_amdgcn_global_load_lds(
      (const __attribute__((address_space(1))) void*)g,
      (__attribute__((address_space(3))) void*)l, 16, 0, 0);
}

// ---------------------------------------------------------------- quantize x
// Exact IEEE division + rintf == jnp.round(x/s) bitwise -> int accum exact.
__global__ __launch_bounds__(256) void quant_x(const float* __restrict__ x,
                                               const float* __restrict__ sptr,
                                               char* __restrict__ xq) {
  const float s = sptr[0];
  const size_t base = ((size_t)blockIdx.x * 256 + threadIdx.x) * 16;
  const float4* xv = (const float4*)(x + base);
  union { char c[16]; i32x4 v; } u;
#pragma unroll
  for (int q = 0; q < 4; ++q) {
    float4 f = xv[q];
    float a = fminf(127.f, fmaxf(-128.f, rintf(f.x / s)));
    float b = fminf(127.f, fmaxf(-128.f, rintf(f.y / s)));
    float c = fminf(127.f, fmaxf(-128.f, rintf(f.z / s)));
    float d = fminf(127.f, fmaxf(-128.f, rintf(f.w / s)));
    u.c[q * 4 + 0] = (char)(int)a;
    u.c[q * 4 + 1] = (char)(int)b;
    u.c[q * 4 + 2] = (char)(int)c;
    u.c[q * 4 + 3] = (char)(int)d;
  }
  *(i32x4*)(xq + base) = u.v;
}

// ---------------- weight i32[K][N] -> i8 Bt[N][K], dword LDS + v_perm -------
// Tile 128K x 64N. Phase1: pack 4 n-bytes -> u32, store lt[n4][k] (pad 132).
// Phase2: ds_read_b128 (4 k-words), v_perm 4x4 byte transpose, 16B K-run out.
__global__ __launch_bounds__(256) void wconv2(const int* __restrict__ w,
                                              char* __restrict__ bt) {
  __shared__ unsigned int lt[16 * 132];  // [n4][k], 132 pad: aligned + bank-spread
  const int k0 = blockIdx.x * 128;
  const int n0 = blockIdx.y * 64;
  const int t = threadIdx.x;
  const int n4 = t & 15;
  const int kr = t >> 4;  // 0..15
#pragma unroll
  for (int i = 0; i < 8; ++i) {
    int k = kr + i * 16;
    int4 v = *(const int4*)(w + (size_t)(k0 + k) * N_DIM + n0 + n4 * 4);
    unsigned int p = ((unsigned)v.x & 0xffu) | (((unsigned)v.y & 0xffu) << 8) |
                     (((unsigned)v.z & 0xffu) << 16) | (((unsigned)v.w) << 24);
    lt[n4 * 132 + k] = p;
  }
  __syncthreads();
  const int n = t >> 2;            // 0..63
  const int n4r = n >> 2;
  const unsigned int bsel = (unsigned)(n & 3);
  const unsigned int sel01 = bsel * 0x101u + 0x0400u;
#pragma unroll
  for (int o = 0; o < 2; ++o) {
    int ks = (t & 3) * 2 + o;      // 0..7
    const unsigned int* base = &lt[n4r * 132 + ks * 16];
    uint4 R;
    unsigned int r[4];
#pragma unroll
    for (int g = 0; g < 4; ++g) {
      uint4 W = *(const uint4*)(base + g * 4);
      unsigned int t0 = __builtin_amdgcn_perm(W.y, W.x, sel01);
      unsigned int t1 = __builtin_amdgcn_perm(W.w, W.z, sel01);
      r[g] = __builtin_amdgcn_perm(t1, t0, 0x05040100u);
    }
    R.x = r[0]; R.y = r[1]; R.z = r[2]; R.w = r[3];
    *(uint4*)(bt + (size_t)(n0 + n) * K_DIM + k0 + ks * 16) = R;
  }
}

// --------------------------- i8 GEMM: 256x256 tile, 8-phase counted-vmcnt ---
// 8 waves (2M x 4N), per-wave 128x64 out; BK=128B; LDS 128KiB:
//   A: [db][256][128] @ db*32768 ; B: 65536 + db*32768 + [256][128]
// Interleaved wave rows: A-frag f -> row f*32+wm*16 (half = f>>2 contiguous);
// B-frag g -> row g*64+wn*16 (half = g>>1 contiguous).
// Gray-code quadrants per tile: (0,0)->(0,1)->(1,1)->(1,0).
// Stage schedule (iter computes T=2i buf0 ph1-4, T+1 buf1 ph5-8):
//  ph1:T+1.A1  ph2:T+1.B0  ph3:T+2.A0  ph4:T+2.B1+vmcnt(4)
//  ph5:T+2.A1  ph6:T+2.B0  ph7:T+3.A0  ph8:T+3.B1+vmcnt(4)
// Each half's stage-issue is >=1 barrier after its last ds_read of the old
// tile in that buffer (A0 read ph1|last ph2-; B1 read ph2; A1 ph3; B0 ph1,4;
// verified per-phase). vmcnt(4) leaves exactly the 2 newest half-tiles
// (4 loads) outstanding -> tile about to be read is fully arrived.
__global__ __launch_bounds__(512, 2) void gemm_i8_8ph(
    const char* __restrict__ Aq, const char* __restrict__ Bt,
    const float* __restrict__ bias, const float* __restrict__ is_ptr,
    const float* __restrict__ ws_ptr, float* __restrict__ out) {
  __shared__ alignas(16) char lds[131072];

  const int nbn = N_DIM / 256;  // 16
  const int bid = blockIdx.x;
  const int cpx = gridDim.x >> 3;  // 64 (512 % 8 == 0 -> bijective)
  const int swz = (bid & 7) * cpx + (bid >> 3);
  const int bm0 = (swz / nbn) * 256;
  const int bn0 = (swz % nbn) * 256;

  const int t = threadIdx.x;
  const int lane = t & 63;
  const int wave = t >> 6;   // 0..7
  const int wm = wave >> 2;  // 0..1
  const int wn = wave & 3;   // 0..3
  const int lr = lane & 15;
  const int kg = lane >> 4;  // 0..3

  // staging: thread t -> row r0=t>>3 (64 rows/load), slot s0=t&7.
  // LDS dest linear (= wave-uniform base + lane*16); global source slot
  // pre-swizzled by r&7 (r&7 == r0&7 since half*128, j*64 are 0 mod 8).
  const int r0 = t >> 3;
  const int s0 = t & 7;
  const int scol = ((s0 ^ (r0 & 7)) << 4);
  const char* aStrip = Aq + (size_t)(bm0 + r0) * K_DIM + scol;
  const char* bStrip = Bt + (size_t)(bn0 + r0) * K_DIM + scol;
  const int dstBase = t * 16;

  // ds_read swizzled slot per k-slice (row&7 == lr&7 for all frag rows)
  int sA[2];
  sA[0] = ((kg ^ (lr & 7)) << 4);
  sA[1] = (((4 + kg) ^ (lr & 7)) << 4);
  const int aBase = (wm * 16 + lr) * 128;
  const int bBase = 65536 + (wn * 16 + lr) * 128;

#define STAGE(strip, matOff, dbuf, kt, half)                                  \
  {                                                                           \
    const char* s_ =                                                          \
        (strip) + (size_t)(kt)*128 + (size_t)(half)*128 * K_DIM;              \
    _Pragma("unroll") for (int j = 0; j < 2; ++j) async_ld16(                 \
        s_ + (size_t)j * 64 * K_DIM,                                          \
        &lds[(matOff) + (dbuf)*32768 + (half)*16384 + j * 8192 + dstBase]);   \
  }

#define LDA(mh, dbuf)                                                         \
  _Pragma("unroll") for (int fi = 0; fi < 4; ++fi)                            \
      _Pragma("unroll") for (int ks = 0; ks < 2; ++ks) aF[fi][ks] =           \
      *(const i32x4*)&lds[(dbuf)*32768 + (mh)*16384 + fi * 4096 + aBase +     \
                          sA[ks]];

#define LDB(nh, dbuf)                                                         \
  _Pragma("unroll") for (int gi = 0; gi < 2; ++gi)                            \
      _Pragma("unroll") for (int ks = 0; ks < 2; ++ks) bF[gi][ks] =           \
      *(const i32x4*)&lds[(dbuf)*32768 + (nh)*16384 + gi * 8192 + bBase +     \
                          sA[ks]];

#define MFMAQ(mh, nh)                                                         \
  __builtin_amdgcn_s_setprio(1);                                              \
  _Pragma("unroll") for (int ks = 0; ks < 2; ++ks)                            \
      _Pragma("unroll") for (int fi = 0; fi < 4; ++fi)                        \
          _Pragma("unroll") for (int gi = 0; gi < 2; ++gi) acc[(mh)*4 + fi]   \
                                                              [(nh)*2 + gi] = \
      __builtin_amdgcn_mfma_i32_16x16x64_i8(                                  \
          aF[fi][ks], bF[gi][ks], acc[(mh)*4 + fi][(nh)*2 + gi], 0, 0, 0);    \
  __builtin_amdgcn_s_setprio(0);

#define FENCE asm volatile("" ::: "memory")
#define BAR __builtin_amdgcn_s_barrier()
#define WAITV(n) asm volatile("s_waitcnt vmcnt(" #n ")" ::: "memory")

  i32x4 acc[8][4];
#pragma unroll
  for (int f = 0; f < 8; ++f)
#pragma unroll
    for (int g = 0; g < 4; ++g) acc[f][g] = (i32x4)(0);
  i32x4 aF[4][2], bF[2][2];

  // Prologue: T0 all 4 halves + T1.A0 + T1.B1; vmcnt(4) -> T0 arrived.
  STAGE(aStrip, 0, 0, 0, 0);
  STAGE(aStrip, 0, 0, 0, 1);
  STAGE(bStrip, 65536, 0, 0, 0);
  STAGE(bStrip, 65536, 0, 0, 1);
  STAGE(aStrip, 0, 1, 1, 0);
  STAGE(bStrip, 65536, 1, 1, 1);
  WAITV(4);
  FENCE; BAR; FENCE;

#pragma unroll 1
  for (int i = 0; i < 15; ++i) {
    const int T = 2 * i;
    // ph1: T q(0,0)
    LDA(0, 0); LDB(0, 0);
    STAGE(aStrip, 0, 1, T + 1, 1);
    FENCE; BAR; MFMAQ(0, 0); FENCE; BAR;
    // ph2: T q(0,1)
    LDB(1, 0);
    STAGE(bStrip, 65536, 1, T + 1, 0);
    FENCE; BAR; MFMAQ(0, 1); FENCE; BAR;
    // ph3: T q(1,1)
    LDA(1, 0);
    STAGE(aStrip, 0, 0, T + 2, 0);
    FENCE; BAR; MFMAQ(1, 1); FENCE; BAR;
    // ph4: T q(1,0)  [vmcnt: T+1 fully arrived before ph5 reads buf1]
    LDB(0, 0);
    STAGE(bStrip, 65536, 0, T + 2, 1);
    WAITV(4);
    FENCE; BAR; MFMAQ(1, 0); FENCE; BAR;
    // ph5: T+1 q(0,0)
    LDA(0, 1); LDB(0, 1);
    STAGE(aStrip, 0, 0, T + 2, 1);
    FENCE; BAR; MFMAQ(0, 0); FENCE; BAR;
    // ph6: T+1 q(0,1)
    LDB(1, 1);
    STAGE(bStrip, 65536, 0, T + 2, 0);
    FENCE; BAR; MFMAQ(0, 1); FENCE; BAR;
    // ph7: T+1 q(1,1)
    LDA(1, 1);
    STAGE(aStrip, 0, 1, T + 3, 0);
    FENCE; BAR; MFMAQ(1, 1); FENCE; BAR;
    // ph8: T+1 q(1,0)  [vmcnt: T+2 fully arrived before next ph1]
    LDB(0, 1);
    STAGE(bStrip, 65536, 1, T + 3, 1);
    WAITV(4);
    FENCE; BAR; MFMAQ(1, 0); FENCE; BAR;
  }

  // Tail: T=30 (buf0), T=31 (buf1); finish staging T31, drain, no prefetch.
  LDA(0, 0); LDB(0, 0);
  STAGE(aStrip, 0, 1, 31, 1);
  FENCE; BAR; MFMAQ(0, 0); FENCE; BAR;
  LDB(1, 0);
  STAGE(bStrip, 65536, 1, 31, 0);
  FENCE; BAR; MFMAQ(0, 1); FENCE; BAR;
  LDA(1, 0);
  FENCE; BAR; MFMAQ(1, 1); FENCE; BAR;
  LDB(0, 0);
  WAITV(0);
  FENCE; BAR; MFMAQ(1, 0); FENCE; BAR;
  LDA(0, 1); LDB(0, 1);
  FENCE; BAR; MFMAQ(0, 0); FENCE; BAR;
  LDB(1, 1);
  FENCE; BAR; MFMAQ(0, 1); FENCE; BAR;
  LDA(1, 1);
  FENCE; BAR; MFMAQ(1, 1); FENCE; BAR;
  LDB(0, 1);
  FENCE; BAR; MFMAQ(1, 0);

  // Epilogue: C/D col=lane&15, row=kg*4+reg (dtype-independent m89/m121).
  const float s = is_ptr[0] * ws_ptr[0];
  float bv[4];
#pragma unroll
  for (int g = 0; g < 4; ++g) bv[g] = bias[bn0 + g * 64 + wn * 16 + lr];
#pragma unroll
  for (int f = 0; f < 8; ++f) {
    const int crow0 = bm0 + f * 32 + wm * 16 + kg * 4;
#pragma unroll
    for (int j = 0; j < 4; ++j) {
      float* orow = out + (size_t)(crow0 + j) * N_DIM;
#pragma unroll
      for (int g = 0; g < 4; ++g)
        orow[bn0 + g * 64 + wn * 16 + lr] = (float)acc[f][g][j] * s + bv[g];
    }
  }
#undef STAGE
#undef LDA
#undef LDB
#undef MFMAQ
#undef FENCE
#undef BAR
#undef WAITV
}

extern "C" void kernel_launch(void* const* d_in, const int* in_sizes, int n_in,
                              void* d_out, int out_size, void* d_ws,
                              size_t ws_size, hipStream_t stream) {
  const float* x = (const float*)d_in[0];
  const int* w = (const int*)d_in[1];
  const float* bias = (const float*)d_in[2];
  const float* isc = (const float*)d_in[3];
  const float* wsc = (const float*)d_in[4];
  float* out = (float*)d_out;

  char* Aq = (char*)d_ws;                          // 32 MiB
  char* Bt = (char*)d_ws + (size_t)M_DIM * K_DIM;  // 16 MiB

  quant_x<<<(M_DIM * K_DIM) / (256 * 16), 256, 0, stream>>>(x, isc, Aq);

  dim3 tg(K_DIM / 128, N_DIM / 64);
  wconv2<<<tg, 256, 0, stream>>>(w, Bt);

  gemm_i8_8ph<<<(M_DIM / 256) * (N_DIM / 256), 512, 0, stream>>>(
      Aq, Bt, bias, isc, wsc, out);
}